// Round 1
// baseline (138.575 us; speedup 1.0000x reference)
//
#include <hip/hip_runtime.h>

#define NSEAS 3
#define NRES  2
#define NCOMP 5
#define KNB   8

// Kernel A: spatial smoothing -> 12 coefficients per station in d_ws.
// params[st*12 + 0] = offset
// params[st*12 + 1] = trend
// params[st*12 + 2+2i] = coeff of sin(2*pi*f_i*t)   (= A_i * cos(phi_i))
// params[st*12 + 3+2i] = coeff of cos(2*pi*f_i*t)   (= A_i * sin(phi_i))
__global__ void smooth_params_kernel(
    const float* __restrict__ constant_offset,
    const float* __restrict__ linear_trend,
    const float* __restrict__ seas_amp,
    const float* __restrict__ seas_phase,
    const float* __restrict__ res_amp,
    const float* __restrict__ res_phase,
    const int*   __restrict__ nb_idx,
    const float* __restrict__ nb_w,
    float* __restrict__ params,
    int N)
{
    int st = blockIdx.x * blockDim.x + threadIdx.x;
    if (st >= N) return;

    const float S = 0.12f, OMS = 1.0f - 0.12f;

    float accA[NSEAS]  = {0.f, 0.f, 0.f};
    float accRe[NSEAS] = {0.f, 0.f, 0.f};
    float accIm[NSEAS] = {0.f, 0.f, 0.f};

    #pragma unroll
    for (int k = 0; k < KNB; ++k) {
        int   nb = nb_idx[st * KNB + k];
        float w  = nb_w[st * KNB + k];
        #pragma unroll
        for (int i = 0; i < NSEAS; ++i) {
            float a = seas_amp[nb * NSEAS + i];
            float p = seas_phase[nb * NSEAS + i];
            float sp, cp;
            sincosf(p, &sp, &cp);
            accA[i]  = fmaf(w, a,  accA[i]);
            accRe[i] = fmaf(w, cp, accRe[i]);
            accIm[i] = fmaf(w, sp, accIm[i]);
        }
    }

    float outp[12];
    outp[0] = constant_offset[st];
    outp[1] = linear_trend[st];

    #pragma unroll
    for (int i = 0; i < NSEAS; ++i) {
        float smA = OMS * seas_amp[st * NSEAS + i] + S * accA[i];
        float sp, cp;
        sincosf(seas_phase[st * NSEAS + i], &sp, &cp);
        float re = OMS * cp + S * accRe[i];
        float im = OMS * sp + S * accIm[i];
        // cos(atan2(im,re)) = re/r, sin(atan2(im,re)) = im/r
        float r   = sqrtf(re * re + im * im);
        float inv = smA / fmaxf(r, 1e-30f);
        outp[2 + 2 * i] = re * inv;   // A*cos(sm_phase)
        outp[3 + 2 * i] = im * inv;   // A*sin(sm_phase)
    }

    #pragma unroll
    for (int i = 0; i < NRES; ++i) {
        float a = res_amp[st * NRES + i];
        float sp, cp;
        sincosf(res_phase[st * NRES + i], &sp, &cp);
        outp[2 + 2 * (NSEAS + i)] = a * cp;
        outp[3 + 2 * (NSEAS + i)] = a * sp;
    }

    #pragma unroll
    for (int j = 0; j < 12; ++j) params[st * 12 + j] = outp[j];
}

// Kernel B: stream the [N_STATIONS x N_TIME] output.
// Each thread owns 4 consecutive t (one float4 store per station); the
// sin/cos time tables for all 5 components live in registers and are
// reused across all stations this block handles.
__global__ __launch_bounds__(256) void signals_kernel(
    const float* __restrict__ time_vector,
    const float* __restrict__ periods,
    const float* __restrict__ res_periods,
    const float* __restrict__ params,
    float* __restrict__ out,
    int N, int T, int spb)
{
    const float TWO_PI = 6.28318530717958647692f;

    int tid = threadIdx.x;
    int t0  = tid * 4;
    bool active = (t0 + 3) < T;   // T=1000 -> tids 0..249 active

    float tv[4];
    float sT[NCOMP][4];
    float cT[NCOMP][4];

    if (active) {
        float4 t4 = *reinterpret_cast<const float4*>(time_vector + t0);
        tv[0] = t4.x; tv[1] = t4.y; tv[2] = t4.z; tv[3] = t4.w;
        #pragma unroll
        for (int i = 0; i < NCOMP; ++i) {
            float f = (i < NSEAS) ? (1.0f / periods[i])
                                  : (1.0f / res_periods[i - NSEAS]);
            #pragma unroll
            for (int j = 0; j < 4; ++j) {
                float arg = TWO_PI * f * tv[j];
                sincosf(arg, &sT[i][j], &cT[i][j]);
            }
        }
    }

    int stBeg = blockIdx.x * spb;
    int stEnd = min(stBeg + spb, N);

    for (int st = stBeg; st < stEnd; ++st) {
        // Wave-uniform param loads (compiler scalarizes these).
        const float* p = params + (size_t)st * 12;
        float off = p[0], trend = p[1];
        float cs[NCOMP], cc[NCOMP];
        #pragma unroll
        for (int i = 0; i < NCOMP; ++i) {
            cs[i] = p[2 + 2 * i];
            cc[i] = p[3 + 2 * i];
        }

        if (active) {
            float v[4];
            #pragma unroll
            for (int j = 0; j < 4; ++j) {
                float acc = fmaf(trend, tv[j], off);
                #pragma unroll
                for (int i = 0; i < NCOMP; ++i) {
                    acc = fmaf(cs[i], sT[i][j], acc);
                    acc = fmaf(cc[i], cT[i][j], acc);
                }
                v[j] = acc;
            }
            float4 o;
            o.x = v[0]; o.y = v[1]; o.z = v[2]; o.w = v[3];
            *reinterpret_cast<float4*>(out + (size_t)st * T + t0) = o;
        }
    }
}

extern "C" void kernel_launch(void* const* d_in, const int* in_sizes, int n_in,
                              void* d_out, int out_size, void* d_ws, size_t ws_size,
                              hipStream_t stream) {
    const float* time_vector     = (const float*)d_in[0];
    const float* constant_offset = (const float*)d_in[1];
    const float* linear_trend    = (const float*)d_in[2];
    const float* seas_amp        = (const float*)d_in[3];
    const float* seas_phase      = (const float*)d_in[4];
    const float* res_amp         = (const float*)d_in[5];
    const float* res_phase       = (const float*)d_in[6];
    const float* res_periods     = (const float*)d_in[7];
    const float* periods         = (const float*)d_in[8];
    const int*   nb_idx          = (const int*)d_in[9];
    const float* nb_w            = (const float*)d_in[10];

    int T = in_sizes[0];
    int N = in_sizes[1];

    float* params = (float*)d_ws;          // N*12 floats = 4.8 MB
    float* out    = (float*)d_out;

    // Kernel A: per-station smoothed coefficients.
    {
        int threads = 256;
        int blocks  = (N + threads - 1) / threads;
        smooth_params_kernel<<<blocks, threads, 0, stream>>>(
            constant_offset, linear_trend, seas_amp, seas_phase,
            res_amp, res_phase, nb_idx, nb_w, params, N);
    }

    // Kernel B: stream the output.
    {
        int grid = 2048;
        int spb  = (N + grid - 1) / grid;
        signals_kernel<<<grid, 256, 0, stream>>>(
            time_vector, periods, res_periods, params, out, N, T, spb);
    }
}